// Round 3
// baseline (709.481 us; speedup 1.0000x reference)
//
#include <hip/hip_runtime.h>
#include <hip/hip_bf16.h>
#include <cstdint>
#include <cstddef>

// Inputs/outputs are fp32 (reference dtype; NaN chain in round 2 proved inputs
// are not bf16 — fp32 read as bf16 yields inf/NaN from mantissa halves).
// Internal node-feature intermediates are stored bf16 for gather bandwidth.
#define FLOATS_ARE_BF16 0

static constexpr int FIN = 128;
static constexpr int HC1 = 128;  // layer1: H=2, C=64, concat

__device__ __forceinline__ float bf2f(unsigned int u) { return __uint_as_float(u << 16); }
__device__ __forceinline__ unsigned short f2bf(float f) {  // round-to-nearest-even
  unsigned int u = __float_as_uint(f);
  return (unsigned short)((u + 0x7fff + ((u >> 16) & 1)) >> 16);
}
__device__ __forceinline__ float lrelu02(float x) { return x > 0.f ? x : 0.2f * x; }

// ============================ CSR build ============================
__global__ __launch_bounds__(256) void count_edges(const int* __restrict__ dst,
                                                   int* __restrict__ cnt, int E) {
  int e = blockIdx.x * 256 + threadIdx.x;
  if (e < E) atomicAdd(&cnt[dst[e]], 1);
}

__global__ __launch_bounds__(256) void scan_block(const int* __restrict__ cnt,
                                                  int* __restrict__ offs,
                                                  int* __restrict__ bsum, int n) {
  __shared__ int sh[256];
  int t = threadIdx.x;
  int i = blockIdx.x * 256 + t;
  int v = (i < n) ? cnt[i] : 0;
  sh[t] = v; __syncthreads();
  for (int d = 1; d < 256; d <<= 1) {
    int w = (t >= d) ? sh[t - d] : 0;
    __syncthreads();
    sh[t] += w;
    __syncthreads();
  }
  if (i < n) offs[i] = sh[t] - v;            // exclusive within block
  if (t == 255) bsum[blockIdx.x] = sh[255];  // block total
}

__global__ __launch_bounds__(512) void scan_top(int* __restrict__ bsum, int nb) {
  __shared__ int sh[512];
  int t = threadIdx.x;
  int v = (t < nb) ? bsum[t] : 0;
  sh[t] = v; __syncthreads();
  for (int d = 1; d < 512; d <<= 1) {
    int w = (t >= d) ? sh[t - d] : 0;
    __syncthreads();
    sh[t] += w;
    __syncthreads();
  }
  if (t < nb) bsum[t] = sh[t] - v;           // exclusive block offsets
}

__global__ __launch_bounds__(256) void scan_add(int* __restrict__ offs,
                                                const int* __restrict__ bsum, int n, int E) {
  int i = blockIdx.x * 256 + threadIdx.x;
  if (i < n) offs[i] += bsum[i >> 8];
  if (i == n) offs[n] = E;
}

__global__ __launch_bounds__(256) void place_edges(const int* __restrict__ src,
                                                   const int* __restrict__ dst,
                                                   const int* __restrict__ offs,
                                                   int* __restrict__ cursor,
                                                   int* __restrict__ ssrc, int E) {
  int e = blockIdx.x * 256 + threadIdx.x;
  if (e < E) {
    int d = dst[e];
    int pos = offs[d] + atomicAdd(&cursor[d], 1);
    ssrc[pos] = src[e];
  }
}

// ============================ GEMM (K=128) ============================
// C[nrows x COLS] = A[nrows x 128] * W[128 x COLS]; fp32 accumulate, bf16 out.
// Block 256 threads; tile 128 rows x COLS; per-thread 8 x (COLS/16).
template <int COLS, bool ABF16>
__global__ __launch_bounds__(256) void gemm_k128(const void* __restrict__ Av,
                                                 const void* __restrict__ Wv,
                                                 unsigned short* __restrict__ C,
                                                 int nrows) {
  constexpr int TN = COLS / 16;  // 8 (COLS=128) or 4 (COLS=64)
  __shared__ float xs[16][132];      // [k][row]
  __shared__ float wsd[16][COLS];    // [k][col]
  const int t = threadIdx.x;
  const int ty = t >> 4, tx = t & 15;
  const int row0 = blockIdx.x * 128;
  float acc[8][TN] = {};

  const int r = t >> 1, hf = t & 1;   // staging: row r, 8-elem half hf
  const int grow = row0 + r;

  for (int k0 = 0; k0 < 128; k0 += 16) {
    // ---- stage A tile: 128 rows x 16 k (transposed into xs[k][row]) ----
    float av[8];
    if (grow < nrows) {
      if constexpr (ABF16) {
        const unsigned short* ap = (const unsigned short*)Av + (size_t)grow * 128 + k0 + hf * 8;
        uint4 u = *(const uint4*)ap;
        av[0] = bf2f(u.x & 0xffffu); av[1] = bf2f(u.x >> 16);
        av[2] = bf2f(u.y & 0xffffu); av[3] = bf2f(u.y >> 16);
        av[4] = bf2f(u.z & 0xffffu); av[5] = bf2f(u.z >> 16);
        av[6] = bf2f(u.w & 0xffffu); av[7] = bf2f(u.w >> 16);
      } else {
        const float* ap = (const float*)Av + (size_t)grow * 128 + k0 + hf * 8;
        float4 f0 = *(const float4*)ap;
        float4 f1 = *(const float4*)(ap + 4);
        av[0] = f0.x; av[1] = f0.y; av[2] = f0.z; av[3] = f0.w;
        av[4] = f1.x; av[5] = f1.y; av[6] = f1.z; av[7] = f1.w;
      }
    } else {
      #pragma unroll
      for (int j = 0; j < 8; j++) av[j] = 0.f;
    }
    #pragma unroll
    for (int j = 0; j < 8; j++) xs[hf * 8 + j][r] = av[j];

    // ---- stage W tile: 16 k x COLS (W is fp32) ----
    if constexpr (COLS == 128) {
      const float* wp = (const float*)Wv + (size_t)(k0 + ty) * 128 + tx * 8;
      float4 f0 = *(const float4*)wp;
      float4 f1 = *(const float4*)(wp + 4);
      wsd[ty][tx * 8 + 0] = f0.x; wsd[ty][tx * 8 + 1] = f0.y;
      wsd[ty][tx * 8 + 2] = f0.z; wsd[ty][tx * 8 + 3] = f0.w;
      wsd[ty][tx * 8 + 4] = f1.x; wsd[ty][tx * 8 + 5] = f1.y;
      wsd[ty][tx * 8 + 6] = f1.z; wsd[ty][tx * 8 + 7] = f1.w;
    } else {  // COLS == 64
      const int kk = t >> 4, c = (t & 15) * 4;
      const float* wp = (const float*)Wv + (size_t)(k0 + kk) * 64 + c;
      float4 f0 = *(const float4*)wp;
      wsd[kk][c + 0] = f0.x; wsd[kk][c + 1] = f0.y; wsd[kk][c + 2] = f0.z; wsd[kk][c + 3] = f0.w;
    }
    __syncthreads();

    // ---- compute ----
    #pragma unroll
    for (int kk = 0; kk < 16; kk++) {
      float a[8];
      #pragma unroll
      for (int i = 0; i < 8; i++) a[i] = xs[kk][ty * 8 + i];
      float b[TN];
      if constexpr (COLS == 128) {
        #pragma unroll
        for (int j = 0; j < 4; j++) { b[j] = wsd[kk][tx * 4 + j]; b[4 + j] = wsd[kk][64 + tx * 4 + j]; }
      } else {
        #pragma unroll
        for (int j = 0; j < TN; j++) b[j] = wsd[kk][tx * 4 + j];
      }
      #pragma unroll
      for (int i = 0; i < 8; i++)
        #pragma unroll
        for (int j = 0; j < TN; j++) acc[i][j] += a[i] * b[j];
    }
    __syncthreads();
  }

  // ---- write C (bf16 internal) ----
  #pragma unroll
  for (int i = 0; i < 8; i++) {
    int rr = row0 + ty * 8 + i;
    if (rr < nrows) {
      if constexpr (COLS == 128) {
        ushort4 v0, v1;
        v0.x = f2bf(acc[i][0]); v0.y = f2bf(acc[i][1]); v0.z = f2bf(acc[i][2]); v0.w = f2bf(acc[i][3]);
        v1.x = f2bf(acc[i][4]); v1.y = f2bf(acc[i][5]); v1.z = f2bf(acc[i][6]); v1.w = f2bf(acc[i][7]);
        *(ushort4*)(C + (size_t)rr * 128 + tx * 4) = v0;
        *(ushort4*)(C + (size_t)rr * 128 + 64 + tx * 4) = v1;
      } else {
        ushort4 v0;
        v0.x = f2bf(acc[i][0]); v0.y = f2bf(acc[i][1]); v0.z = f2bf(acc[i][2]); v0.w = f2bf(acc[i][3]);
        *(ushort4*)(C + (size_t)rr * 64 + tx * 4) = v0;
      }
    }
  }
}

// ============================ attention logits ============================
// asrc[n,h] = sum_c h[n,h,c]*att_src[h,c]; adst likewise. One wave per node.
// hfeat is bf16 [n, H*64]; att vectors are fp32.
template <int H>
__global__ __launch_bounds__(256) void attn_logits(const unsigned short* __restrict__ hfeat,
                                                   const float* __restrict__ att_s,
                                                   const float* __restrict__ att_d,
                                                   float* __restrict__ asrc,
                                                   float* __restrict__ adst, int n) {
  constexpr int HC = H * 64;
  int node = (int)((blockIdx.x * (unsigned)blockDim.x + threadIdx.x) >> 6);
  int lane = threadIdx.x & 63;
  if (node >= n) return;
  float ss = 0.f, sd = 0.f;
  if constexpr (H == 2) {
    unsigned int u = ((const unsigned int*)(hfeat + (size_t)node * HC))[lane];
    float hv0 = bf2f(u & 0xffffu), hv1 = bf2f(u >> 16);
    int ch = lane * 2;
    float as0 = att_s[ch], as1 = att_s[ch + 1];
    float ad0 = att_d[ch], ad1 = att_d[ch + 1];
    ss = hv0 * as0 + hv1 * as1;
    sd = hv0 * ad0 + hv1 * ad1;
  } else {
    float hv = bf2f(hfeat[(size_t)node * HC + lane]);
    ss = hv * att_s[lane];
    sd = hv * att_d[lane];
  }
  #pragma unroll
  for (int d = (H == 1 ? 32 : 16); d >= 1; d >>= 1) {
    ss += __shfl_xor(ss, d);
    sd += __shfl_xor(sd, d);
  }
  int gl = (H == 2) ? (lane & 31) : lane;
  int hd = (H == 2) ? (lane >> 5) : 0;
  if (gl == 0) {
    asrc[(size_t)node * H + hd] = ss;
    adst[(size_t)node * H + hd] = sd;
  }
}

// ============================ softmax-aggregate (gather) ============================
// One wave per destination node; bf16 hfeat in; out bf16 (internal) or fp32 (final).
template <int H, bool ELU_OUT, bool F32OUT>
__global__ __launch_bounds__(256) void agg_gather(const unsigned short* __restrict__ hfeat,
                                                  const float* __restrict__ asrc,
                                                  const float* __restrict__ adst,
                                                  const int* __restrict__ offs,
                                                  const int* __restrict__ ssrc,
                                                  const float* __restrict__ bias,
                                                  void* __restrict__ outv, int n) {
  constexpr int HC = H * 64;
  constexpr int PER = HC / 64;  // 2 (H=2) or 1 (H=1)
  int node = (int)((blockIdx.x * (unsigned)blockDim.x + threadIdx.x) >> 6);
  int lane = threadIdx.x & 63;
  if (node >= n) return;
  const int hd = (H == 2) ? (lane >> 5) : 0;
  const float ad = adst[(size_t)node * H + hd];
  const float e_self = lrelu02(asrc[(size_t)node * H + hd] + ad);
  const int beg = offs[node], end = offs[node + 1];

  // ---- pass 1: max logit over in-edges + self ----
  float m = e_self;
  const int gl = (H == 2) ? (lane & 31) : lane;
  const int gs = (H == 2) ? 32 : 64;
  for (int j = beg + gl; j < end; j += gs) {
    int s = ssrc[j];
    m = fmaxf(m, lrelu02(asrc[(size_t)s * H + hd] + ad));
  }
  #pragma unroll
  for (int d = gs >> 1; d >= 1; d >>= 1) m = fmaxf(m, __shfl_xor(m, d));

  // ---- pass 2: exp-sum + weighted accumulate (unnormalized) ----
  float p0 = __expf(e_self - m);
  float denom = p0;
  float acc[PER];
  if constexpr (H == 2) {
    unsigned int u = ((const unsigned int*)(hfeat + (size_t)node * HC))[lane];
    acc[0] = p0 * bf2f(u & 0xffffu);
    acc[1] = p0 * bf2f(u >> 16);
  } else {
    acc[0] = p0 * bf2f(hfeat[(size_t)node * HC + lane]);
  }
  for (int j = beg; j < end; j++) {
    int s = ssrc[j];
    float p = __expf(lrelu02(asrc[(size_t)s * H + hd] + ad) - m);
    denom += p;
    if constexpr (H == 2) {
      unsigned int u = ((const unsigned int*)(hfeat + (size_t)s * HC))[lane];
      acc[0] += p * bf2f(u & 0xffffu);
      acc[1] += p * bf2f(u >> 16);
    } else {
      acc[0] += p * bf2f(hfeat[(size_t)s * HC + lane]);
    }
  }

  const float inv = 1.f / denom;
  #pragma unroll
  for (int k = 0; k < PER; k++) {
    int ch = lane * PER + k;
    float v = acc[k] * inv + bias[ch];
    if (ELU_OUT) v = v > 0.f ? v : (__expf(v) - 1.f);
    if constexpr (F32OUT)
      ((float*)outv)[(size_t)node * HC + ch] = v;
    else
      ((unsigned short*)outv)[(size_t)node * HC + ch] = f2bf(v);
  }
}

// ============================ launch ============================
extern "C" void kernel_launch(void* const* d_in, const int* in_sizes, int n_in,
                              void* d_out, int out_size, void* d_ws, size_t ws_size,
                              hipStream_t stream) {
  const int N = in_sizes[0] / FIN;      // 100000
  const int E = in_sizes[1] / 2;        // 1600000

  const void*  x   = d_in[0];
  const int*   ei  = (const int*)d_in[1];
  const void*  W1  = d_in[2];
  const float* as1 = (const float*)d_in[3];
  const float* ad1 = (const float*)d_in[4];
  const float* b1  = (const float*)d_in[5];
  const void*  W2  = d_in[6];
  const float* as2 = (const float*)d_in[7];
  const float* ad2 = (const float*)d_in[8];
  const float* b2  = (const float*)d_in[9];

  const int* e_src = ei;
  const int* e_dst = ei + E;

  // ---- workspace carve (256B aligned) ----
  char* p = (char*)d_ws;
  auto carve = [&](size_t bytes) {
    char* q = p;
    p += (bytes + 255) & ~(size_t)255;
    return (void*)q;
  };
  unsigned short* h1   = (unsigned short*)carve((size_t)N * HC1 * 2);  // bf16; reused for h2
  unsigned short* buf2 = (unsigned short*)carve((size_t)N * HC1 * 2);  // bf16 layer1 out (elu'd)
  float* asrc1 = (float*)carve((size_t)N * 2 * 4);
  float* adst1 = (float*)carve((size_t)N * 2 * 4);
  float* asrc2 = (float*)carve((size_t)N * 4);
  float* adst2 = (float*)carve((size_t)N * 4);
  int* counts  = (int*)carve((size_t)2 * N * 4);  // counts[N] + cursor[N] contiguous
  int* cursor  = counts + N;
  int* offs    = (int*)carve((size_t)(N + 1) * 4);
  int* bsum    = (int*)carve(512 * 4);
  int* ssrc    = (int*)carve((size_t)E * 4);
  unsigned short* h2 = h1;  // reuse: h1 dead after layer-1 aggregation

  const int nb = (N + 255) / 256;              // 391 scan blocks
  const int egrid = (E + 255) / 256;
  const int wgrid = (int)(((size_t)N * 64 + 255) / 256);
  const int ggrid = (N + 127) / 128;

  // ---- CSR build (shared by both layers) ----
  hipMemsetAsync(counts, 0, (size_t)2 * N * 4, stream);  // zeros counts AND cursor
  count_edges<<<egrid, 256, 0, stream>>>(e_dst, counts, E);
  scan_block<<<nb, 256, 0, stream>>>(counts, offs, bsum, N);
  scan_top<<<1, 512, 0, stream>>>(bsum, nb);
  scan_add<<<(N + 256) / 256, 256, 0, stream>>>(offs, bsum, N, E);
  place_edges<<<egrid, 256, 0, stream>>>(e_src, e_dst, offs, cursor, ssrc, E);

  // ---- layer 1 ----
  gemm_k128<128, false><<<ggrid, 256, 0, stream>>>(x, W1, h1, N);
  attn_logits<2><<<wgrid, 256, 0, stream>>>(h1, as1, ad1, asrc1, adst1, N);
  agg_gather<2, true, false><<<wgrid, 256, 0, stream>>>(h1, asrc1, adst1, offs, ssrc, b1, buf2, N);

  // ---- layer 2 ----
  gemm_k128<64, true><<<ggrid, 256, 0, stream>>>(buf2, W2, h2, N);
  attn_logits<1><<<wgrid, 256, 0, stream>>>(h2, as2, ad2, asrc2, adst2, N);
  agg_gather<1, false, true><<<wgrid, 256, 0, stream>>>(h2, asrc2, adst2, offs, ssrc, b2,
                                                        d_out, N);
}

// Round 4
// 575.478 us; speedup vs baseline: 1.2329x; 1.2329x over previous
//
#include <hip/hip_runtime.h>
#include <hip/hip_bf16.h>
#include <cstdint>
#include <cstddef>

// Inputs/outputs fp32 (reference dtype). Internal node features stored bf16.
static constexpr int FIN = 128;
static constexpr int HC1 = 128;  // layer1: H=2, C=64, concat

__device__ __forceinline__ float bf2f(unsigned int u) { return __uint_as_float(u << 16); }
__device__ __forceinline__ unsigned short f2bf(float f) {  // round-to-nearest-even
  unsigned int u = __float_as_uint(f);
  return (unsigned short)((u + 0x7fff + ((u >> 16) & 1)) >> 16);
}
__device__ __forceinline__ float lrelu02(float x) { return x > 0.f ? x : 0.2f * x; }
#define NEG_INF __int_as_float(0xff800000)

// ============================ CSR build ============================
__global__ __launch_bounds__(256) void count_edges(const int* __restrict__ dst,
                                                   int* __restrict__ cnt, int E) {
  int e = blockIdx.x * 256 + threadIdx.x;
  if (e < E) atomicAdd(&cnt[dst[e]], 1);
}

__global__ __launch_bounds__(256) void scan_block(const int* __restrict__ cnt,
                                                  int* __restrict__ offs,
                                                  int* __restrict__ bsum, int n) {
  __shared__ int sh[256];
  int t = threadIdx.x;
  int i = blockIdx.x * 256 + t;
  int v = (i < n) ? cnt[i] : 0;
  sh[t] = v; __syncthreads();
  for (int d = 1; d < 256; d <<= 1) {
    int w = (t >= d) ? sh[t - d] : 0;
    __syncthreads();
    sh[t] += w;
    __syncthreads();
  }
  if (i < n) offs[i] = sh[t] - v;
  if (t == 255) bsum[blockIdx.x] = sh[255];
}

__global__ __launch_bounds__(512) void scan_top(int* __restrict__ bsum, int nb) {
  __shared__ int sh[512];
  int t = threadIdx.x;
  int v = (t < nb) ? bsum[t] : 0;
  sh[t] = v; __syncthreads();
  for (int d = 1; d < 512; d <<= 1) {
    int w = (t >= d) ? sh[t - d] : 0;
    __syncthreads();
    sh[t] += w;
    __syncthreads();
  }
  if (t < nb) bsum[t] = sh[t] - v;
}

__global__ __launch_bounds__(256) void scan_add(int* __restrict__ offs,
                                                const int* __restrict__ bsum, int n, int E) {
  int i = blockIdx.x * 256 + threadIdx.x;
  if (i < n) offs[i] += bsum[i >> 8];
  if (i == n) offs[n] = E;
}

__global__ __launch_bounds__(256) void place_edges(const int* __restrict__ src,
                                                   const int* __restrict__ dst,
                                                   const int* __restrict__ offs,
                                                   int* __restrict__ cursor,
                                                   int* __restrict__ ssrc, int E) {
  int e = blockIdx.x * 256 + threadIdx.x;
  if (e < E) {
    int d = dst[e];
    int pos = offs[d] + atomicAdd(&cursor[d], 1);
    ssrc[pos] = src[e];
  }
}

// ============================ GEMM (K=128) ============================
template <int COLS, bool ABF16>
__global__ __launch_bounds__(256) void gemm_k128(const void* __restrict__ Av,
                                                 const void* __restrict__ Wv,
                                                 unsigned short* __restrict__ C,
                                                 int nrows) {
  constexpr int TN = COLS / 16;
  __shared__ float xs[16][132];
  __shared__ float wsd[16][COLS];
  const int t = threadIdx.x;
  const int ty = t >> 4, tx = t & 15;
  const int row0 = blockIdx.x * 128;
  float acc[8][TN] = {};

  const int r = t >> 1, hf = t & 1;
  const int grow = row0 + r;

  for (int k0 = 0; k0 < 128; k0 += 16) {
    float av[8];
    if (grow < nrows) {
      if constexpr (ABF16) {
        const unsigned short* ap = (const unsigned short*)Av + (size_t)grow * 128 + k0 + hf * 8;
        uint4 u = *(const uint4*)ap;
        av[0] = bf2f(u.x & 0xffffu); av[1] = bf2f(u.x >> 16);
        av[2] = bf2f(u.y & 0xffffu); av[3] = bf2f(u.y >> 16);
        av[4] = bf2f(u.z & 0xffffu); av[5] = bf2f(u.z >> 16);
        av[6] = bf2f(u.w & 0xffffu); av[7] = bf2f(u.w >> 16);
      } else {
        const float* ap = (const float*)Av + (size_t)grow * 128 + k0 + hf * 8;
        float4 f0 = *(const float4*)ap;
        float4 f1 = *(const float4*)(ap + 4);
        av[0] = f0.x; av[1] = f0.y; av[2] = f0.z; av[3] = f0.w;
        av[4] = f1.x; av[5] = f1.y; av[6] = f1.z; av[7] = f1.w;
      }
    } else {
      #pragma unroll
      for (int j = 0; j < 8; j++) av[j] = 0.f;
    }
    #pragma unroll
    for (int j = 0; j < 8; j++) xs[hf * 8 + j][r] = av[j];

    if constexpr (COLS == 128) {
      const float* wp = (const float*)Wv + (size_t)(k0 + ty) * 128 + tx * 8;
      float4 f0 = *(const float4*)wp;
      float4 f1 = *(const float4*)(wp + 4);
      wsd[ty][tx * 8 + 0] = f0.x; wsd[ty][tx * 8 + 1] = f0.y;
      wsd[ty][tx * 8 + 2] = f0.z; wsd[ty][tx * 8 + 3] = f0.w;
      wsd[ty][tx * 8 + 4] = f1.x; wsd[ty][tx * 8 + 5] = f1.y;
      wsd[ty][tx * 8 + 6] = f1.z; wsd[ty][tx * 8 + 7] = f1.w;
    } else {
      const int kk = t >> 4, c = (t & 15) * 4;
      const float* wp = (const float*)Wv + (size_t)(k0 + kk) * 64 + c;
      float4 f0 = *(const float4*)wp;
      wsd[kk][c + 0] = f0.x; wsd[kk][c + 1] = f0.y; wsd[kk][c + 2] = f0.z; wsd[kk][c + 3] = f0.w;
    }
    __syncthreads();

    #pragma unroll
    for (int kk = 0; kk < 16; kk++) {
      float a[8];
      #pragma unroll
      for (int i = 0; i < 8; i++) a[i] = xs[kk][ty * 8 + i];
      float b[TN];
      if constexpr (COLS == 128) {
        #pragma unroll
        for (int j = 0; j < 4; j++) { b[j] = wsd[kk][tx * 4 + j]; b[4 + j] = wsd[kk][64 + tx * 4 + j]; }
      } else {
        #pragma unroll
        for (int j = 0; j < TN; j++) b[j] = wsd[kk][tx * 4 + j];
      }
      #pragma unroll
      for (int i = 0; i < 8; i++)
        #pragma unroll
        for (int j = 0; j < TN; j++) acc[i][j] += a[i] * b[j];
    }
    __syncthreads();
  }

  #pragma unroll
  for (int i = 0; i < 8; i++) {
    int rr = row0 + ty * 8 + i;
    if (rr < nrows) {
      if constexpr (COLS == 128) {
        ushort4 v0, v1;
        v0.x = f2bf(acc[i][0]); v0.y = f2bf(acc[i][1]); v0.z = f2bf(acc[i][2]); v0.w = f2bf(acc[i][3]);
        v1.x = f2bf(acc[i][4]); v1.y = f2bf(acc[i][5]); v1.z = f2bf(acc[i][6]); v1.w = f2bf(acc[i][7]);
        *(ushort4*)(C + (size_t)rr * 128 + tx * 4) = v0;
        *(ushort4*)(C + (size_t)rr * 128 + 64 + tx * 4) = v1;
      } else {
        ushort4 v0;
        v0.x = f2bf(acc[i][0]); v0.y = f2bf(acc[i][1]); v0.z = f2bf(acc[i][2]); v0.w = f2bf(acc[i][3]);
        *(ushort4*)(C + (size_t)rr * 64 + tx * 4) = v0;
      }
    }
  }
}

// ============================ attention logits ============================
template <int H>
__global__ __launch_bounds__(256) void attn_logits(const unsigned short* __restrict__ hfeat,
                                                   const float* __restrict__ att_s,
                                                   const float* __restrict__ att_d,
                                                   float* __restrict__ asrc,
                                                   float* __restrict__ adst, int n) {
  constexpr int HC = H * 64;
  int node = (int)((blockIdx.x * (unsigned)blockDim.x + threadIdx.x) >> 6);
  int lane = threadIdx.x & 63;
  if (node >= n) return;
  float ss = 0.f, sd = 0.f;
  if constexpr (H == 2) {
    unsigned int u = ((const unsigned int*)(hfeat + (size_t)node * HC))[lane];
    float hv0 = bf2f(u & 0xffffu), hv1 = bf2f(u >> 16);
    int ch = lane * 2;
    ss = hv0 * att_s[ch] + hv1 * att_s[ch + 1];
    sd = hv0 * att_d[ch] + hv1 * att_d[ch + 1];
  } else {
    float hv = bf2f(hfeat[(size_t)node * HC + lane]);
    ss = hv * att_s[lane];
    sd = hv * att_d[lane];
  }
  #pragma unroll
  for (int d = (H == 1 ? 32 : 16); d >= 1; d >>= 1) {
    ss += __shfl_xor(ss, d);
    sd += __shfl_xor(sd, d);
  }
  int gl = (H == 2) ? (lane & 31) : lane;
  int hd = (H == 2) ? (lane >> 5) : 0;
  if (gl == 0) {
    asrc[(size_t)node * H + hd] = ss;
    adst[(size_t)node * H + hd] = sd;
  }
}

// ============= softmax-aggregate: batched flash-style, one wave per node =============
// H==2: chunk=32 edges; lane half h computes head-h p for the same 32 edges.
//       Inner loop: one 256B row per edge, all 64 lanes (lane -> ch 2l,2l+1).
// H==1: chunk=64 edges; inner loop: 2 edges/iter (two 128B rows fill 64 lanes);
//       cross-half combine at end. Online softmax rescaling (exact).
template <int H, bool ELU_OUT, bool F32OUT>
__global__ __launch_bounds__(256) void agg_gather(const unsigned short* __restrict__ hfeat,
                                                  const float* __restrict__ asrc,
                                                  const float* __restrict__ adst,
                                                  const int* __restrict__ offs,
                                                  const int* __restrict__ ssrc,
                                                  const float* __restrict__ bias,
                                                  void* __restrict__ outv, int n) {
  int node = (int)((blockIdx.x * (unsigned)blockDim.x + threadIdx.x) >> 6);
  int lane = threadIdx.x & 63;
  if (node >= n) return;
  const int hd = lane >> 5;
  const int beg = offs[node], end = offs[node + 1];

  float adh, m, acc0, acc1, d;
  if constexpr (H == 2) {
    float2 adv = ((const float2*)adst)[node];
    float2 asv = ((const float2*)asrc)[node];
    adh = hd ? adv.y : adv.x;
    m = lrelu02((hd ? asv.y : asv.x) + adh);  // e_self per head
    unsigned int u = ((const unsigned int*)((const char*)hfeat + ((size_t)node << 8)))[lane];
    acc0 = bf2f(u & 0xffffu);  // p_self = 1
    acc1 = bf2f(u >> 16);
  } else {
    adh = adst[node];
    m = lrelu02(asrc[node] + adh);
    if (hd == 0) {
      unsigned int u = ((const unsigned int*)((const char*)hfeat + ((size_t)node << 7)))[lane];
      acc0 = bf2f(u & 0xffffu);
      acc1 = bf2f(u >> 16);
    } else {
      acc0 = 0.f; acc1 = 0.f;
    }
  }
  d = 1.f;  // p_self

  constexpr int CH = (H == 2) ? 32 : 64;
  for (int pos = beg; pos < end; pos += CH) {
    const int len = min(CH, end - pos);
    // ---- batch phase: lanes load chunk edges' (s, a), compute e ----
    int li = (H == 2) ? (lane & 31) : lane;
    bool valid = li < len;
    int s_l = valid ? ssrc[pos + li] : 0;
    float e_l;
    if constexpr (H == 2) {
      float a = asrc[(s_l << 1) + hd];
      e_l = valid ? lrelu02(a + adh) : NEG_INF;
    } else {
      float a = asrc[s_l];
      e_l = valid ? lrelu02(a + adh) : NEG_INF;
    }
    // ---- chunk max (per head for H==2: reduce within 32-lane half) ----
    float mc = e_l;
    #pragma unroll
    for (int dlt = CH >> 1; dlt >= 1; dlt >>= 1) mc = fmaxf(mc, __shfl_xor(mc, dlt));
    float m_new = fmaxf(m, mc);
    float f = __expf(m - m_new);
    float p_l = __expf(e_l - m_new);
    // ---- chunk denom ----
    float sc = p_l;
    #pragma unroll
    for (int dlt = CH >> 1; dlt >= 1; dlt >>= 1) sc += __shfl_xor(sc, dlt);
    d = d * f + sc;
    acc0 *= f; acc1 *= f;
    m = m_new;
    // ---- inner gather loop ----
    if constexpr (H == 2) {
      const int srcLane = lane & 32;  // p for own head lives at j + 32*hd
      #pragma unroll 4
      for (int j = 0; j < len; j++) {
        int s = __shfl(s_l, j);
        float p = __shfl(p_l, j + srcLane);
        unsigned int u = ((const unsigned int*)((const char*)hfeat + ((size_t)(unsigned)s << 8)))[lane];
        acc0 += p * bf2f(u & 0xffffu);
        acc1 += p * bf2f(u >> 16);
      }
    } else {
      const int npair = (len + 1) >> 1;
      #pragma unroll 4
      for (int i = 0; i < npair; i++) {
        int jj = 2 * i + hd;  // hi half takes odd edge; jj<=len<64 when odd tail -> p=0
        int s = __shfl(s_l, jj);
        float p = __shfl(p_l, jj);
        unsigned int u = ((const unsigned int*)((const char*)hfeat + ((size_t)(unsigned)s << 7)))[lane & 31];
        acc0 += p * bf2f(u & 0xffffu);
        acc1 += p * bf2f(u >> 16);
      }
    }
  }

  if constexpr (H == 1) {  // combine halves (each half accumulated different edges)
    acc0 += __shfl_xor(acc0, 32);
    acc1 += __shfl_xor(acc1, 32);
  }

  const float inv = 1.f / d;
  if constexpr (H == 2) {
    float2 bv = ((const float2*)bias)[lane];
    float v0 = acc0 * inv + bv.x;
    float v1 = acc1 * inv + bv.y;
    if (ELU_OUT) {
      v0 = v0 > 0.f ? v0 : (__expf(v0) - 1.f);
      v1 = v1 > 0.f ? v1 : (__expf(v1) - 1.f);
    }
    if constexpr (F32OUT) {
      ((float2*)outv)[(size_t)node * 64 + lane] = make_float2(v0, v1);
    } else {
      unsigned int pk = (unsigned int)f2bf(v0) | ((unsigned int)f2bf(v1) << 16);
      ((unsigned int*)outv)[(size_t)node * 64 + lane] = pk;
    }
  } else {
    if (hd == 0) {
      float2 bv = ((const float2*)bias)[lane];  // lane<32 -> ch 2l,2l+1
      float v0 = acc0 * inv + bv.x;
      float v1 = acc1 * inv + bv.y;
      if (ELU_OUT) {
        v0 = v0 > 0.f ? v0 : (__expf(v0) - 1.f);
        v1 = v1 > 0.f ? v1 : (__expf(v1) - 1.f);
      }
      if constexpr (F32OUT) {
        ((float2*)outv)[(size_t)node * 32 + lane] = make_float2(v0, v1);
      } else {
        unsigned int pk = (unsigned int)f2bf(v0) | ((unsigned int)f2bf(v1) << 16);
        ((unsigned int*)outv)[(size_t)node * 32 + lane] = pk;
      }
    }
  }
}

// ============================ launch ============================
extern "C" void kernel_launch(void* const* d_in, const int* in_sizes, int n_in,
                              void* d_out, int out_size, void* d_ws, size_t ws_size,
                              hipStream_t stream) {
  const int N = in_sizes[0] / FIN;      // 100000
  const int E = in_sizes[1] / 2;        // 1600000

  const void*  x   = d_in[0];
  const int*   ei  = (const int*)d_in[1];
  const void*  W1  = d_in[2];
  const float* as1 = (const float*)d_in[3];
  const float* ad1 = (const float*)d_in[4];
  const float* b1  = (const float*)d_in[5];
  const void*  W2  = d_in[6];
  const float* as2 = (const float*)d_in[7];
  const float* ad2 = (const float*)d_in[8];
  const float* b2  = (const float*)d_in[9];

  const int* e_src = ei;
  const int* e_dst = ei + E;

  char* p = (char*)d_ws;
  auto carve = [&](size_t bytes) {
    char* q = p;
    p += (bytes + 255) & ~(size_t)255;
    return (void*)q;
  };
  unsigned short* h1   = (unsigned short*)carve((size_t)N * HC1 * 2);
  unsigned short* buf2 = (unsigned short*)carve((size_t)N * HC1 * 2);
  float* asrc1 = (float*)carve((size_t)N * 2 * 4);
  float* adst1 = (float*)carve((size_t)N * 2 * 4);
  float* asrc2 = (float*)carve((size_t)N * 4);
  float* adst2 = (float*)carve((size_t)N * 4);
  int* counts  = (int*)carve((size_t)2 * N * 4);
  int* cursor  = counts + N;
  int* offs    = (int*)carve((size_t)(N + 1) * 4);
  int* bsum    = (int*)carve(512 * 4);
  int* ssrc    = (int*)carve((size_t)E * 4);
  unsigned short* h2 = h1;

  const int nb = (N + 255) / 256;
  const int egrid = (E + 255) / 256;
  const int wgrid = (int)(((size_t)N * 64 + 255) / 256);
  const int ggrid = (N + 127) / 128;

  hipMemsetAsync(counts, 0, (size_t)2 * N * 4, stream);
  count_edges<<<egrid, 256, 0, stream>>>(e_dst, counts, E);
  scan_block<<<nb, 256, 0, stream>>>(counts, offs, bsum, N);
  scan_top<<<1, 512, 0, stream>>>(bsum, nb);
  scan_add<<<(N + 256) / 256, 256, 0, stream>>>(offs, bsum, N, E);
  place_edges<<<egrid, 256, 0, stream>>>(e_src, e_dst, offs, cursor, ssrc, E);

  gemm_k128<128, false><<<ggrid, 256, 0, stream>>>(x, W1, h1, N);
  attn_logits<2><<<wgrid, 256, 0, stream>>>(h1, as1, ad1, asrc1, adst1, N);
  agg_gather<2, true, false><<<wgrid, 256, 0, stream>>>(h1, asrc1, adst1, offs, ssrc, b1, buf2, N);

  gemm_k128<64, true><<<ggrid, 256, 0, stream>>>(buf2, W2, h2, N);
  attn_logits<1><<<wgrid, 256, 0, stream>>>(h2, as2, ad2, asrc2, adst2, N);
  agg_gather<1, false, true><<<wgrid, 256, 0, stream>>>(h2, asrc2, adst2, offs, ssrc, b2,
                                                        d_out, N);
}

// Round 5
// 464.251 us; speedup vs baseline: 1.5282x; 1.2396x over previous
//
#include <hip/hip_runtime.h>
#include <hip/hip_bf16.h>
#include <cstdint>
#include <cstddef>

// Inputs/outputs fp32 (reference dtype). Internal node features stored bf16.
static constexpr int FIN = 128;
static constexpr int HC1 = 128;  // layer1: H=2, C=64, concat
static constexpr int EPB = 4096; // edges per block in bucket_scatter

__device__ __forceinline__ float bf2f(unsigned int u) { return __uint_as_float(u << 16); }
__device__ __forceinline__ unsigned short f2bf(float f) {  // round-to-nearest-even
  unsigned int u = __float_as_uint(f);
  return (unsigned short)((u + 0x7fff + ((u >> 16) & 1)) >> 16);
}
__device__ __forceinline__ float lrelu02(float x) { return x > 0.f ? x : 0.2f * x; }
__device__ __forceinline__ int rl_i(int v, int l) { return __builtin_amdgcn_readlane(v, l); }
__device__ __forceinline__ float rl_f(float v, int l) {
  return __int_as_float(__builtin_amdgcn_readlane(__float_as_int(v), l));
}
#define NEG_INF __int_as_float(0xff800000)

// ============================ bucket-sorted CSR build ============================
// bucket(d) = d >> 8 (256 dst per bucket). All edges of a dst land in one bucket,
// each bucket is processed by exactly one block downstream -> LDS cursors, no
// global random scatter (round-4 place_edges: 107 MB WRITE_SIZE for 6.4 MB data).

__global__ __launch_bounds__(256) void bucket_hist(const int* __restrict__ dst,
                                                   int* __restrict__ bhist, int E, int NB) {
  __shared__ int lh[512];
  int t = threadIdx.x;
  lh[t] = 0; lh[t + 256] = 0;
  __syncthreads();
  int e0 = blockIdx.x * EPB;
  #pragma unroll
  for (int i = 0; i < EPB / 256; i++) {
    int e = e0 + i * 256 + t;
    if (e < E) atomicAdd(&lh[dst[e] >> 8], 1);
  }
  __syncthreads();
  for (int x = t; x < NB; x += 256) {
    int c = lh[x];
    if (c > 0) atomicAdd(&bhist[x], c);
  }
}

__global__ __launch_bounds__(512) void scan_buckets(const int* __restrict__ bhist,
                                                    int* __restrict__ boffs, int n) {
  __shared__ int sh[512];
  int t = threadIdx.x;
  int v = (t < n) ? bhist[t] : 0;
  sh[t] = v; __syncthreads();
  for (int d = 1; d < 512; d <<= 1) {
    int w = (t >= d) ? sh[t - d] : 0;
    __syncthreads();
    sh[t] += w;
    __syncthreads();
  }
  if (t <= n) boffs[t] = sh[t] - v;  // exclusive; t==n gives total
}

// Two-pass per-block scatter: LDS count -> one global atomic per touched bucket
// -> LDS-ranked scatter. Writes go to ~NB sequential streams (lines fill fully).
__global__ __launch_bounds__(256) void bucket_scatter(const int* __restrict__ src,
                                                      const int* __restrict__ dst,
                                                      const int* __restrict__ boffs,
                                                      int* __restrict__ gcur,
                                                      unsigned int* __restrict__ sorted,
                                                      int E, int NB) {
  __shared__ int lh[512];
  int t = threadIdx.x;
  lh[t] = 0; lh[t + 256] = 0;
  __syncthreads();
  int e0 = blockIdx.x * EPB;
  #pragma unroll
  for (int i = 0; i < EPB / 256; i++) {
    int e = e0 + i * 256 + t;
    if (e < E) atomicAdd(&lh[dst[e] >> 8], 1);
  }
  __syncthreads();
  for (int x = t; x < NB; x += 256) {
    int c = lh[x];
    lh[x] = (c > 0) ? (boffs[x] + atomicAdd(&gcur[x], c)) : 0;
  }
  __syncthreads();
  #pragma unroll
  for (int i = 0; i < EPB / 256; i++) {
    int e = e0 + i * 256 + t;
    if (e < E) {
      int d = dst[e];
      int pos = atomicAdd(&lh[d >> 8], 1);
      sorted[pos] = ((unsigned int)src[e] << 8) | (unsigned int)(d & 255);  // src<2^17
    }
  }
}

__global__ __launch_bounds__(256) void bucket_count(const unsigned int* __restrict__ sorted,
                                                    const int* __restrict__ boffs,
                                                    int* __restrict__ counts, int N) {
  __shared__ int cnt[256];
  int b = blockIdx.x, t = threadIdx.x;
  cnt[t] = 0; __syncthreads();
  int beg = boffs[b], end = boffs[b + 1];
  for (int p = beg + t; p < end; p += 256)
    atomicAdd(&cnt[sorted[p] & 255u], 1);
  __syncthreads();
  int d = b * 256 + t;
  if (d < N) counts[d] = cnt[t];
}

__global__ __launch_bounds__(256) void scan_block(const int* __restrict__ cnt,
                                                  int* __restrict__ offs,
                                                  int* __restrict__ bsum, int n) {
  __shared__ int sh[256];
  int t = threadIdx.x;
  int i = blockIdx.x * 256 + t;
  int v = (i < n) ? cnt[i] : 0;
  sh[t] = v; __syncthreads();
  for (int d = 1; d < 256; d <<= 1) {
    int w = (t >= d) ? sh[t - d] : 0;
    __syncthreads();
    sh[t] += w;
    __syncthreads();
  }
  if (i < n) offs[i] = sh[t] - v;
  if (t == 255) bsum[blockIdx.x] = sh[255];
}

__global__ __launch_bounds__(512) void scan_top(int* __restrict__ bsum, int nb) {
  __shared__ int sh[512];
  int t = threadIdx.x;
  int v = (t < nb) ? bsum[t] : 0;
  sh[t] = v; __syncthreads();
  for (int d = 1; d < 512; d <<= 1) {
    int w = (t >= d) ? sh[t - d] : 0;
    __syncthreads();
    sh[t] += w;
    __syncthreads();
  }
  if (t < nb) bsum[t] = sh[t] - v;
}

__global__ __launch_bounds__(256) void scan_add(int* __restrict__ offs,
                                                const int* __restrict__ bsum, int n, int E) {
  int i = blockIdx.x * 256 + threadIdx.x;
  if (i < n) offs[i] += bsum[i >> 8];
  if (i == n) offs[n] = E;
}

// One block per bucket: every edge of a dst is in this block -> LDS cursor.
// ssrc writes land in the bucket's contiguous CSR window (~16 KB).
__global__ __launch_bounds__(256) void bucket_place(const unsigned int* __restrict__ sorted,
                                                    const int* __restrict__ boffs,
                                                    const int* __restrict__ offs,
                                                    int* __restrict__ ssrc, int N) {
  __shared__ int offl[256];
  __shared__ int cur[256];
  int b = blockIdx.x, t = threadIdx.x;
  int d = b * 256 + t;
  offl[t] = (d < N) ? offs[d] : 0;
  cur[t] = 0;
  __syncthreads();
  int beg = boffs[b], end = boffs[b + 1];
  for (int p = beg + t; p < end; p += 256) {
    unsigned int pk = sorted[p];
    int dl = pk & 255u;
    int r = atomicAdd(&cur[dl], 1);
    ssrc[offl[dl] + r] = (int)(pk >> 8);
  }
}

// ============================ GEMM (K=128) ============================
template <int COLS, bool ABF16>
__global__ __launch_bounds__(256) void gemm_k128(const void* __restrict__ Av,
                                                 const void* __restrict__ Wv,
                                                 unsigned short* __restrict__ C,
                                                 int nrows) {
  constexpr int TN = COLS / 16;
  __shared__ float xs[16][132];
  __shared__ float wsd[16][COLS];
  const int t = threadIdx.x;
  const int ty = t >> 4, tx = t & 15;
  const int row0 = blockIdx.x * 128;
  float acc[8][TN] = {};

  const int r = t >> 1, hf = t & 1;
  const int grow = row0 + r;

  for (int k0 = 0; k0 < 128; k0 += 16) {
    float av[8];
    if (grow < nrows) {
      if constexpr (ABF16) {
        const unsigned short* ap = (const unsigned short*)Av + (size_t)grow * 128 + k0 + hf * 8;
        uint4 u = *(const uint4*)ap;
        av[0] = bf2f(u.x & 0xffffu); av[1] = bf2f(u.x >> 16);
        av[2] = bf2f(u.y & 0xffffu); av[3] = bf2f(u.y >> 16);
        av[4] = bf2f(u.z & 0xffffu); av[5] = bf2f(u.z >> 16);
        av[6] = bf2f(u.w & 0xffffu); av[7] = bf2f(u.w >> 16);
      } else {
        const float* ap = (const float*)Av + (size_t)grow * 128 + k0 + hf * 8;
        float4 f0 = *(const float4*)ap;
        float4 f1 = *(const float4*)(ap + 4);
        av[0] = f0.x; av[1] = f0.y; av[2] = f0.z; av[3] = f0.w;
        av[4] = f1.x; av[5] = f1.y; av[6] = f1.z; av[7] = f1.w;
      }
    } else {
      #pragma unroll
      for (int j = 0; j < 8; j++) av[j] = 0.f;
    }
    #pragma unroll
    for (int j = 0; j < 8; j++) xs[hf * 8 + j][r] = av[j];

    if constexpr (COLS == 128) {
      const float* wp = (const float*)Wv + (size_t)(k0 + ty) * 128 + tx * 8;
      float4 f0 = *(const float4*)wp;
      float4 f1 = *(const float4*)(wp + 4);
      wsd[ty][tx * 8 + 0] = f0.x; wsd[ty][tx * 8 + 1] = f0.y;
      wsd[ty][tx * 8 + 2] = f0.z; wsd[ty][tx * 8 + 3] = f0.w;
      wsd[ty][tx * 8 + 4] = f1.x; wsd[ty][tx * 8 + 5] = f1.y;
      wsd[ty][tx * 8 + 6] = f1.z; wsd[ty][tx * 8 + 7] = f1.w;
    } else {
      const int kk = t >> 4, c = (t & 15) * 4;
      const float* wp = (const float*)Wv + (size_t)(k0 + kk) * 64 + c;
      float4 f0 = *(const float4*)wp;
      wsd[kk][c + 0] = f0.x; wsd[kk][c + 1] = f0.y; wsd[kk][c + 2] = f0.z; wsd[kk][c + 3] = f0.w;
    }
    __syncthreads();

    #pragma unroll
    for (int kk = 0; kk < 16; kk++) {
      float a[8];
      #pragma unroll
      for (int i = 0; i < 8; i++) a[i] = xs[kk][ty * 8 + i];
      float b[TN];
      if constexpr (COLS == 128) {
        #pragma unroll
        for (int j = 0; j < 4; j++) { b[j] = wsd[kk][tx * 4 + j]; b[4 + j] = wsd[kk][64 + tx * 4 + j]; }
      } else {
        #pragma unroll
        for (int j = 0; j < TN; j++) b[j] = wsd[kk][tx * 4 + j];
      }
      #pragma unroll
      for (int i = 0; i < 8; i++)
        #pragma unroll
        for (int j = 0; j < TN; j++) acc[i][j] += a[i] * b[j];
    }
    __syncthreads();
  }

  #pragma unroll
  for (int i = 0; i < 8; i++) {
    int rr = row0 + ty * 8 + i;
    if (rr < nrows) {
      if constexpr (COLS == 128) {
        ushort4 v0, v1;
        v0.x = f2bf(acc[i][0]); v0.y = f2bf(acc[i][1]); v0.z = f2bf(acc[i][2]); v0.w = f2bf(acc[i][3]);
        v1.x = f2bf(acc[i][4]); v1.y = f2bf(acc[i][5]); v1.z = f2bf(acc[i][6]); v1.w = f2bf(acc[i][7]);
        *(ushort4*)(C + (size_t)rr * 128 + tx * 4) = v0;
        *(ushort4*)(C + (size_t)rr * 128 + 64 + tx * 4) = v1;
      } else {
        ushort4 v0;
        v0.x = f2bf(acc[i][0]); v0.y = f2bf(acc[i][1]); v0.z = f2bf(acc[i][2]); v0.w = f2bf(acc[i][3]);
        *(ushort4*)(C + (size_t)rr * 64 + tx * 4) = v0;
      }
    }
  }
}

// ============================ attention logits ============================
template <int H>
__global__ __launch_bounds__(256) void attn_logits(const unsigned short* __restrict__ hfeat,
                                                   const float* __restrict__ att_s,
                                                   const float* __restrict__ att_d,
                                                   float* __restrict__ asrc,
                                                   float* __restrict__ adst, int n) {
  constexpr int HC = H * 64;
  int node = (int)((blockIdx.x * (unsigned)blockDim.x + threadIdx.x) >> 6);
  int lane = threadIdx.x & 63;
  if (node >= n) return;
  float ss = 0.f, sd = 0.f;
  if constexpr (H == 2) {
    unsigned int u = ((const unsigned int*)(hfeat + (size_t)node * HC))[lane];
    float hv0 = bf2f(u & 0xffffu), hv1 = bf2f(u >> 16);
    int ch = lane * 2;
    ss = hv0 * att_s[ch] + hv1 * att_s[ch + 1];
    sd = hv0 * att_d[ch] + hv1 * att_d[ch + 1];
  } else {
    float hv = bf2f(hfeat[(size_t)node * HC + lane]);
    ss = hv * att_s[lane];
    sd = hv * att_d[lane];
  }
  #pragma unroll
  for (int d = (H == 1 ? 32 : 16); d >= 1; d >>= 1) {
    ss += __shfl_xor(ss, d);
    sd += __shfl_xor(sd, d);
  }
  int gl = (H == 2) ? (lane & 31) : lane;
  int hd = (H == 2) ? (lane >> 5) : 0;
  if (gl == 0) {
    asrc[(size_t)node * H + hd] = ss;
    adst[(size_t)node * H + hd] = sd;
  }
}

// ============= softmax-aggregate: batched flash-style, one wave per node =============
// Inner gather uses readlane (uniform index -> no ds_bpermute latency in chain).
template <int H, bool ELU_OUT, bool F32OUT>
__global__ __launch_bounds__(256) void agg_gather(const unsigned short* __restrict__ hfeat,
                                                  const float* __restrict__ asrc,
                                                  const float* __restrict__ adst,
                                                  const int* __restrict__ offs,
                                                  const int* __restrict__ ssrc,
                                                  const float* __restrict__ bias,
                                                  void* __restrict__ outv, int n) {
  int node = (int)((blockIdx.x * (unsigned)blockDim.x + threadIdx.x) >> 6);
  int lane = threadIdx.x & 63;
  if (node >= n) return;
  const int hd = lane >> 5;
  const int beg = offs[node], end = offs[node + 1];

  float adh, m, acc0, acc1, d;
  if constexpr (H == 2) {
    float2 adv = ((const float2*)adst)[node];
    float2 asv = ((const float2*)asrc)[node];
    adh = hd ? adv.y : adv.x;
    m = lrelu02((hd ? asv.y : asv.x) + adh);  // e_self per head
    unsigned int u = ((const unsigned int*)((const char*)hfeat + ((size_t)node << 8)))[lane];
    acc0 = bf2f(u & 0xffffu);  // p_self = 1
    acc1 = bf2f(u >> 16);
  } else {
    adh = adst[node];
    m = lrelu02(asrc[node] + adh);
    if (hd == 0) {
      unsigned int u = ((const unsigned int*)((const char*)hfeat + ((size_t)node << 7)))[lane];
      acc0 = bf2f(u & 0xffffu);
      acc1 = bf2f(u >> 16);
    } else {
      acc0 = 0.f; acc1 = 0.f;
    }
  }
  d = 1.f;  // p_self

  constexpr int CH = (H == 2) ? 32 : 64;
  for (int pos = beg; pos < end; pos += CH) {
    const int len = min(CH, end - pos);
    int li = (H == 2) ? (lane & 31) : lane;
    bool valid = li < len;
    int s_l = valid ? ssrc[pos + li] : 0;
    float e_l;
    if constexpr (H == 2) {
      float a = asrc[(s_l << 1) + hd];
      e_l = valid ? lrelu02(a + adh) : NEG_INF;
    } else {
      float a = asrc[s_l];
      e_l = valid ? lrelu02(a + adh) : NEG_INF;
    }
    float mc = e_l;
    #pragma unroll
    for (int dlt = CH >> 1; dlt >= 1; dlt >>= 1) mc = fmaxf(mc, __shfl_xor(mc, dlt));
    float m_new = fmaxf(m, mc);
    float f = __expf(m - m_new);
    float p_l = __expf(e_l - m_new);  // 0 for invalid lanes
    float sc = p_l;
    #pragma unroll
    for (int dlt = CH >> 1; dlt >= 1; dlt >>= 1) sc += __shfl_xor(sc, dlt);
    d = d * f + sc;
    acc0 *= f; acc1 *= f;
    m = m_new;

    if constexpr (H == 2) {
      #pragma unroll 8
      for (int j = 0; j < len; j++) {
        int s = rl_i(s_l, j);
        float pa = rl_f(p_l, j);
        float pb = rl_f(p_l, j + 32);
        float p = hd ? pb : pa;
        unsigned int u = ((const unsigned int*)((const char*)hfeat + ((size_t)(unsigned)s << 8)))[lane];
        acc0 += p * bf2f(u & 0xffffu);
        acc1 += p * bf2f(u >> 16);
      }
    } else {
      const int npair = (len + 1) >> 1;
      #pragma unroll 8
      for (int i = 0; i < npair; i++) {
        int jj = 2 * i;
        int s0 = rl_i(s_l, jj), s1 = rl_i(s_l, jj + 1);
        float p0 = rl_f(p_l, jj), p1 = rl_f(p_l, jj + 1);  // p=0 past len (odd tail)
        int s = hd ? s1 : s0;
        float p = hd ? p1 : p0;
        unsigned int u = ((const unsigned int*)((const char*)hfeat + ((size_t)(unsigned)s << 7)))[lane & 31];
        acc0 += p * bf2f(u & 0xffffu);
        acc1 += p * bf2f(u >> 16);
      }
    }
  }

  if constexpr (H == 1) {  // halves accumulated different edges
    acc0 += __shfl_xor(acc0, 32);
    acc1 += __shfl_xor(acc1, 32);
  }

  const float inv = 1.f / d;
  if constexpr (H == 2) {
    float2 bv = ((const float2*)bias)[lane];
    float v0 = acc0 * inv + bv.x;
    float v1 = acc1 * inv + bv.y;
    if (ELU_OUT) {
      v0 = v0 > 0.f ? v0 : (__expf(v0) - 1.f);
      v1 = v1 > 0.f ? v1 : (__expf(v1) - 1.f);
    }
    if constexpr (F32OUT) {
      ((float2*)outv)[(size_t)node * 64 + lane] = make_float2(v0, v1);
    } else {
      unsigned int pk = (unsigned int)f2bf(v0) | ((unsigned int)f2bf(v1) << 16);
      ((unsigned int*)outv)[(size_t)node * 64 + lane] = pk;
    }
  } else {
    if (hd == 0) {
      float2 bv = ((const float2*)bias)[lane];
      float v0 = acc0 * inv + bv.x;
      float v1 = acc1 * inv + bv.y;
      if (ELU_OUT) {
        v0 = v0 > 0.f ? v0 : (__expf(v0) - 1.f);
        v1 = v1 > 0.f ? v1 : (__expf(v1) - 1.f);
      }
      if constexpr (F32OUT) {
        ((float2*)outv)[(size_t)node * 32 + lane] = make_float2(v0, v1);
      } else {
        unsigned int pk = (unsigned int)f2bf(v0) | ((unsigned int)f2bf(v1) << 16);
        ((unsigned int*)outv)[(size_t)node * 32 + lane] = pk;
      }
    }
  }
}

// ============================ launch ============================
extern "C" void kernel_launch(void* const* d_in, const int* in_sizes, int n_in,
                              void* d_out, int out_size, void* d_ws, size_t ws_size,
                              hipStream_t stream) {
  const int N = in_sizes[0] / FIN;      // 100000
  const int E = in_sizes[1] / 2;        // 1600000

  const void*  x   = d_in[0];
  const int*   ei  = (const int*)d_in[1];
  const void*  W1  = d_in[2];
  const float* as1 = (const float*)d_in[3];
  const float* ad1 = (const float*)d_in[4];
  const float* b1  = (const float*)d_in[5];
  const void*  W2  = d_in[6];
  const float* as2 = (const float*)d_in[7];
  const float* ad2 = (const float*)d_in[8];
  const float* b2  = (const float*)d_in[9];

  const int* e_src = ei;
  const int* e_dst = ei + E;

  char* p = (char*)d_ws;
  auto carve = [&](size_t bytes) {
    char* q = p;
    p += (bytes + 255) & ~(size_t)255;
    return (void*)q;
  };
  unsigned short* h1   = (unsigned short*)carve((size_t)N * HC1 * 2);
  unsigned short* buf2 = (unsigned short*)carve((size_t)N * HC1 * 2);
  float* asrc1 = (float*)carve((size_t)N * 2 * 4);
  float* adst1 = (float*)carve((size_t)N * 2 * 4);
  float* asrc2 = (float*)carve((size_t)N * 4);
  float* adst2 = (float*)carve((size_t)N * 4);
  int* counts  = (int*)carve((size_t)N * 4);
  int* offs    = (int*)carve((size_t)(N + 1) * 4);
  int* bsum    = (int*)carve(512 * 4);
  int* bhist   = (int*)carve((size_t)2 * 512 * 4);  // bhist[512] + gcur[512], one memset
  int* gcur    = bhist + 512;
  int* boffs   = (int*)carve(513 * 4);
  unsigned int* sorted = (unsigned int*)carve((size_t)E * 4);
  int* ssrc    = (int*)carve((size_t)E * 4);
  unsigned short* h2 = h1;  // reuse: h1 dead after layer-1 aggregation

  const int NB = (N + 255) >> 8;               // 391 buckets
  const int nb = (N + 255) / 256;              // scan blocks (=NB)
  const int sgrid = (E + EPB - 1) / EPB;       // 391
  const int wgrid = (int)(((size_t)N * 64 + 255) / 256);
  const int ggrid = (N + 127) / 128;

  // ---- CSR build (bucket-sorted, shared by both layers) ----
  hipMemsetAsync(bhist, 0, (size_t)2 * 512 * 4, stream);
  bucket_hist<<<sgrid, 256, 0, stream>>>(e_dst, bhist, E, NB);
  scan_buckets<<<1, 512, 0, stream>>>(bhist, boffs, NB);
  bucket_scatter<<<sgrid, 256, 0, stream>>>(e_src, e_dst, boffs, gcur, sorted, E, NB);
  bucket_count<<<NB, 256, 0, stream>>>(sorted, boffs, counts, N);
  scan_block<<<nb, 256, 0, stream>>>(counts, offs, bsum, N);
  scan_top<<<1, 512, 0, stream>>>(bsum, nb);
  scan_add<<<(N + 256) / 256, 256, 0, stream>>>(offs, bsum, N, E);
  bucket_place<<<NB, 256, 0, stream>>>(sorted, boffs, offs, ssrc, N);

  // ---- layer 1 ----
  gemm_k128<128, false><<<ggrid, 256, 0, stream>>>(x, W1, h1, N);
  attn_logits<2><<<wgrid, 256, 0, stream>>>(h1, as1, ad1, asrc1, adst1, N);
  agg_gather<2, true, false><<<wgrid, 256, 0, stream>>>(h1, asrc1, adst1, offs, ssrc, b1, buf2, N);

  // ---- layer 2 ----
  gemm_k128<64, true><<<ggrid, 256, 0, stream>>>(buf2, W2, h2, N);
  attn_logits<1><<<wgrid, 256, 0, stream>>>(h2, as2, ad2, asrc2, adst2, N);
  agg_gather<1, false, true><<<wgrid, 256, 0, stream>>>(h2, asrc2, adst2, offs, ssrc, b2,
                                                        d_out, N);
}